// Round 16
// baseline (202.056 us; speedup 1.0000x reference)
//
#include <hip/hip_runtime.h>
#include <cmath>

namespace {

typedef _Float16 half8 __attribute__((ext_vector_type(8)));
typedef float f32x4 __attribute__((ext_vector_type(4)));

constexpr int M_TOTAL = 32 * 1024;   // B*T
constexpr int K_CH    = 512;
constexpr int NV      = 640;         // G*V
constexpr int D_CV    = 128;
constexpr int NSLOT   = 10;          // 640/64

constexpr int BM = 128, BN = 128, BK = 64;
constexpr int NTILE  = NV / BN;        // 5
constexpr int NPANEL = M_TOTAL / BM;   // 256
constexpr int NBLK   = NTILE * NPANEL; // 1280 (divisible by 8)
constexpr int KT     = K_CH / BK;      // 8

// f16 hi-only logit error: sigma ~ 3.4e-4 per logit. Margin tau = 6e-3
// (>12 sigma of the top-2 error difference) -> P(missed flip) < 1e-30
// over all 65536 rows. Flag rate ~0.3-0.5%.
constexpr float TAU = 6e-3f;

__device__ __forceinline__ void gld16(const void* g, void* l) {
  __builtin_amdgcn_global_load_lds(
      (__attribute__((address_space(1))) void*)g,
      (__attribute__((address_space(3))) void*)l, 16, 0, 0);
}

// ---------- prep: W[512][640] f32 -> Wth f16 [640][512] + Wtf f32 [640][512]
__global__ __launch_bounds__(256)
void prep_w2(const float* __restrict__ W, _Float16* __restrict__ Wth,
             float* __restrict__ Wtf)
{
  __shared__ float tile[32][33];
  const int bk = blockIdx.x & 15;
  const int bn = blockIdx.x >> 4;
  const int k0 = bk * 32, n0 = bn * 32;
  const int t = threadIdx.x;
  const int nn = t & 31, kk = t >> 5;
  #pragma unroll
  for (int p = 0; p < 4; ++p)
    tile[kk + p * 8][nn] = W[(size_t)(k0 + kk + p * 8) * NV + n0 + nn];
  __syncthreads();
  const int kx = t & 31, nx = t >> 5;
  #pragma unroll
  for (int p = 0; p < 4; ++p) {
    const float v = tile[kx][nx + p * 8];
    const size_t o = (size_t)(n0 + nx + p * 8) * K_CH + k0 + kx;
    Wth[o] = (_Float16)v;
    Wtf[o] = v;
  }
}

// ---------- pass 1: f16 hi-only MFMA GEMM (BK=64) + per-slot top-2 ----------
// A staged global f32 -> regs -> cvt f16 -> ds_write (swizzled slot);
// B staged via global_load_lds with pre-swizzled global chunk (rule #21).
// LDS per buffer: A f16 [128 rows][64] at [0,16K), B f16 at [16K,32K).
__global__ __launch_bounds__(256, 2)
void gvq_p1(const float* __restrict__ x, const _Float16* __restrict__ Wth,
            const float* __restrict__ bias, const float* __restrict__ u,
            float* __restrict__ pval, int* __restrict__ pidx,
            float* __restrict__ psec)
{
  __shared__ __align__(16) char lds[2][32768];   // 64 KB -> 2 blocks/CU

  const int chunk = NBLK / 8;
  const int nid   = (blockIdx.x % 8) * chunk + blockIdx.x / 8;
  const int panel = nid / NTILE, ntile = nid % NTILE;
  const int m0 = panel * BM, n0 = ntile * BN;

  const int t    = threadIdx.x;
  const int wv   = t >> 6, lane = t & 63;
  const int wr   = wv >> 1, wc = wv & 1;      // 2x2 wave grid, 64x64 each
  const int li   = lane & 15, q = lane >> 4;

  // A staging: thread carries natural global f32 chunk (coalesced reads),
  // writes to swizzled LDS slot s = chunk ^ (row&7).
  const int ar0   = t >> 3;                    // row base 0..31 (+i*32)
  const int aslot = (t & 7) ^ ((t >> 3) & 7);  // LDS 16B slot
  const float* pxa = x + (size_t)(m0 + ar0) * K_CH + (t & 7) * 8;
  // B staging: gld16 dest is linear; global chunk pre-swizzled.
  const int bgc = (t & 7) ^ ((t >> 3) & 7);
  const _Float16* pbh = Wth + (size_t)(n0 + (t >> 3)) * K_CH + bgc * 8;

  f32x4 acc[4][4];
  #pragma unroll
  for (int i = 0; i < 4; ++i)
    #pragma unroll
    for (int j = 0; j < 4; ++j) acc[i][j] = (f32x4){0.f, 0.f, 0.f, 0.f};

  f32x4 aR[8];   // in-flight A: 4 row-groups x 2 float4 (32 f32)
  auto issueA = [&](int kt) {
    #pragma unroll
    for (int i = 0; i < 4; ++i)
      #pragma unroll
      for (int j = 0; j < 2; ++j)
        aR[i * 2 + j] = *reinterpret_cast<const f32x4*>(
            pxa + (size_t)i * 32 * K_CH + kt * BK + j * 4);
  };
  auto issueB = [&](int kt, int b) {   // 4 gld16
    char* Lb = lds[b] + 16384;
    #pragma unroll
    for (int i = 0; i < 4; ++i)
      gld16(pbh + (size_t)i * 32 * K_CH + kt * BK, Lb + i * 4096 + wv * 1024);
  };
  auto writeA = [&](int b) {           // cvt + 4 ds_write_b128
    char* La = lds[b];
    #pragma unroll
    for (int i = 0; i < 4; ++i) {
      half8 h;
      #pragma unroll
      for (int e = 0; e < 4; ++e) {
        h[e]     = (_Float16)aR[i * 2][e];
        h[4 + e] = (_Float16)aR[i * 2 + 1][e];
      }
      *reinterpret_cast<half8*>(La + (i * 32 + ar0) * 128 + aslot * 16) = h;
    }
  };

  const int arow = (wr * 64 + li) * 128;            // + fm*2048 (bytes)
  const int brow = 16384 + (wc * 64 + li) * 128;    // + fn*2048

  issueA(0);
  issueB(0, 0);
  #pragma unroll
  for (int kt = 0; kt < KT; ++kt) {
    const int cur = kt & 1;
    writeA(cur);                        // compiler auto-waits aR's vmcnt
    if (kt + 1 < KT) { issueA(kt + 1); issueB(kt + 1, cur ^ 1); }
    if (kt + 1 < KT) asm volatile("s_waitcnt vmcnt(12) lgkmcnt(0)" ::: "memory");
    else             asm volatile("s_waitcnt vmcnt(0) lgkmcnt(0)"  ::: "memory");
    __builtin_amdgcn_s_barrier();       // A writes + B gld16 visible
    __builtin_amdgcn_sched_barrier(0);

    const char* L = lds[cur];
    #pragma unroll
    for (int ksub = 0; ksub < 2; ++ksub) {
      const int soff = (((ksub * 4 + q) ^ (li & 7)) << 4);
      half8 ah[4], bh[4];
      #pragma unroll
      for (int f = 0; f < 4; ++f) {
        ah[f] = *reinterpret_cast<const half8*>(L + arow + f * 2048 + soff);
        bh[f] = *reinterpret_cast<const half8*>(L + brow + f * 2048 + soff);
      }
      #pragma unroll
      for (int fm = 0; fm < 4; ++fm)
        #pragma unroll
        for (int fn = 0; fn < 4; ++fn)
          acc[fm][fn] = __builtin_amdgcn_mfma_f32_16x16x32_f16(
              ah[fm], bh[fn], acc[fm][fn], 0, 0, 0);
    }
    __builtin_amdgcn_sched_barrier(0);
    __builtin_amdgcn_s_barrier();       // reads of buf[cur] done
  }

  // ---- epilogue: approx vals + per-slot top-2 (max, idx, second) ----
  const int colbase = n0 + wc * 64 + li;
  float bb[4];
  #pragma unroll
  for (int fn = 0; fn < 4; ++fn) bb[fn] = bias[colbase + fn * 16];

  const int slot = ntile * 2 + wc;
  #pragma unroll
  for (int fm = 0; fm < 4; ++fm) {
    #pragma unroll
    for (int r = 0; r < 4; ++r) {
      const int m = m0 + wr * 64 + fm * 16 + q * 4 + r;
      float v1 = -INFINITY, v2 = -INFINITY;
      int   i1 = 0x7fffffff;
      #pragma unroll
      for (int fn = 0; fn < 4; ++fn) {
        const float uu  = u[(size_t)m * NV + colbase + fn * 16];
        const float gg  = -__logf(-__logf(uu));
        const float val = acc[fm][fn][r] + bb[fn] + gg;
        const int   n   = colbase + fn * 16;
        if (val > v1)      { v2 = v1; v1 = val; i1 = n; }  // first max kept
        else if (val > v2) { v2 = val; }
      }
      #pragma unroll
      for (int s = 1; s <= 8; s <<= 1) {   // merge across 16 li-lanes
        const float ov1 = __shfl_xor(v1, s);
        const int   oi1 = __shfl_xor(i1, s);
        const float ov2 = __shfl_xor(v2, s);
        const bool  win = (v1 > ov1) || (v1 == ov1 && i1 < oi1);
        const float mv2 = fmaxf(v2, ov2);
        if (win) { v2 = fmaxf(mv2, ov1); }
        else     { v2 = fmaxf(mv2, v1); v1 = ov1; i1 = oi1; }
      }
      if (li == 0) {
        pval[(size_t)m * NSLOT + slot] = v1;
        pidx[(size_t)m * NSLOT + slot] = i1;
        psec[(size_t)m * NSLOT + slot] = v2;
      }
    }
  }
}

// ---------- gather: reduce 5 slots, margin-flag, write approx winner --------
__global__ __launch_bounds__(256)
void gvq_gather3(const float* __restrict__ pval, const int* __restrict__ pidx,
                 const float* __restrict__ psec, const float* __restrict__ cv,
                 float* __restrict__ out, int* __restrict__ flagCnt,
                 int* __restrict__ flagList)
{
  const int tid  = threadIdx.x;
  const int w    = tid >> 6;
  const int lane = tid & 63;
  const int m    = blockIdx.x * 4 + w;
  const int g    = lane >> 5;

  const size_t base = (size_t)m * NSLOT + g * 5;
  float bv = pval[base], sec = -INFINITY;
  int   bi = pidx[base], bs = 0;
  #pragma unroll
  for (int s = 1; s < 5; ++s) {
    const float v = pval[base + s];
    const int   i = pidx[base + s];
    if (v > bv || (v == bv && i < bi)) { sec = fmaxf(sec, bv); bv = v; bi = i; bs = s; }
    else                               { sec = fmaxf(sec, v); }
  }
  sec = fmaxf(sec, psec[base + bs]);   // true runner-up incl. winner's slot

  if ((lane & 31) == 0 && (bv - sec) <= TAU) {
    const int idx = atomicAdd(flagCnt, 1);
    flagList[idx] = m * 2 + g;
  }
  const float4 src = *reinterpret_cast<const float4*>(
      &cv[(size_t)bi * D_CV + (lane & 31) * 4]);
  *reinterpret_cast<float4*>(&out[(size_t)m * 256 + lane * 4]) = src;
}

// ---------- fix: exact fp32 recompute of all 320 cols for flagged rows ------
__global__ __launch_bounds__(256)
void gvq_fix(const float* __restrict__ x, const float* __restrict__ Wtf,
             const float* __restrict__ bias, const float* __restrict__ u,
             const float* __restrict__ cv, float* __restrict__ out,
             const int* __restrict__ flagCnt, const int* __restrict__ flagList)
{
  __shared__ float xs[4][K_CH];
  const int w    = threadIdx.x >> 6;
  const int lane = threadIdx.x & 63;
  const int nW   = gridDim.x * 4;
  const int wid  = blockIdx.x * 4 + w;
  const int cnt  = *flagCnt;

  for (int it = wid; it < cnt; it += nW) {
    const int id = flagList[it];
    const int m = id >> 1, g = id & 1;
    // stage x row (wave-local; in-wave lgkm ordering suffices)
    {
      f32x4* dst = reinterpret_cast<f32x4*>(xs[w]);
      const f32x4* src = reinterpret_cast<const f32x4*>(x + (size_t)m * K_CH);
      dst[lane]      = src[lane];
      dst[lane + 64] = src[lane + 64];
    }
    float bvv = -INFINITY;
    int   bn  = 0x7fffffff;
    #pragma unroll 1
    for (int c = 0; c < 5; ++c) {
      const int n = g * 320 + c * 64 + lane;
      const float* wt = Wtf + (size_t)n * K_CH;
      float acc = 0.f;
      for (int k = 0; k < K_CH; k += 4) {     // serial ascending fp32
        acc = fmaf(xs[w][k + 0], wt[k + 0], acc);
        acc = fmaf(xs[w][k + 1], wt[k + 1], acc);
        acc = fmaf(xs[w][k + 2], wt[k + 2], acc);
        acc = fmaf(xs[w][k + 3], wt[k + 3], acc);
      }
      const float uu  = u[(size_t)m * NV + n];
      const float gg  = -logf(-logf(uu));
      const float val = acc + bias[n] + gg;
      if (val > bvv) { bvv = val; bn = n; }   // ascending n keeps first max
    }
    #pragma unroll
    for (int s = 1; s <= 32; s <<= 1) {
      const float ov = __shfl_xor(bvv, s);
      const int   oi = __shfl_xor(bn, s);
      if (ov > bvv || (ov == bvv && oi < bn)) { bvv = ov; bn = oi; }
    }
    if (lane < 32) {
      const float4 src = *reinterpret_cast<const float4*>(
          &cv[(size_t)bn * D_CV + lane * 4]);
      *reinterpret_cast<float4*>(&out[(size_t)m * 256 + g * 128 + lane * 4]) = src;
    }
  }
}

}  // namespace

extern "C" void kernel_launch(void* const* d_in, const int* in_sizes, int n_in,
                              void* d_out, int out_size, void* d_ws, size_t ws_size,
                              hipStream_t stream)
{
  const float* x    = (const float*)d_in[0];
  const float* W    = (const float*)d_in[1];
  const float* bias = (const float*)d_in[2];
  const float* cv   = (const float*)d_in[3];
  const float* u    = (const float*)d_in[4];
  float* out = (float*)d_out;

  _Float16* Wth   = (_Float16*)d_ws;
  float*    Wtf   = (float*)(Wth + (size_t)NV * K_CH);
  float*    pval  = Wtf + (size_t)NV * K_CH;
  int*      pidx  = (int*)(pval + (size_t)M_TOTAL * NSLOT);
  float*    psec  = (float*)(pidx + (size_t)M_TOTAL * NSLOT);
  int*      flagCnt  = (int*)(psec + (size_t)M_TOTAL * NSLOT);
  int*      flagList = flagCnt + 4;

  hipMemsetAsync(flagCnt, 0, sizeof(int), stream);
  hipLaunchKernelGGL(prep_w2, dim3(320), dim3(256), 0, stream, W, Wth, Wtf);
  hipLaunchKernelGGL(gvq_p1, dim3(NBLK), dim3(256), 0, stream,
                     x, Wth, bias, u, pval, pidx, psec);
  hipLaunchKernelGGL(gvq_gather3, dim3(M_TOTAL / 4), dim3(256), 0, stream,
                     pval, pidx, psec, cv, out, flagCnt, flagList);
  hipLaunchKernelGGL(gvq_fix, dim3(128), dim3(256), 0, stream,
                     x, Wtf, bias, u, cv, out, flagCnt, flagList);
}